// Round 11
// baseline (264.100 us; speedup 1.0000x reference)
//
#include <hip/hip_runtime.h>
#include <math.h>

#define NND 50000
#define NED 800000
#define NGR 2048
#define NT  1024          // rad-table entries (uniform in xe = exp(-d))
#define CAP 64            // per-node geo bucket capacity (Poisson(16): P(>64) ~ 1e-20)
#define NB  256           // coarse bins
#define NPB 196           // nodes per bin (256*196 = 50176 >= NND)
#define BCAP 3840         // coarse-bin capacity (mean 3136, +12 sigma)
#define LCAP 48           // per-block LDS bin capacity (mean 16, +8 sigma)
#define LSTR 49           // LDS row stride
#define BIN_BLOCKS 196    // ceil(NED / 4096)
#define GEO_BLOCKS 256
#define TBL_BLOCKS 16     // 16 blocks x 64 entries = NT

// exp(-5) and derived RBF constants, computed in double then rounded once.
constexpr double dSTART = 0.006737946999085467;
constexpr float  K_START = (float)dSTART;
constexpr float  K_STEP  = (float)((1.0 - dSTART) / 127.0);
constexpr float  K_BETA  = (float)(1.0 / ((2.0/128.0*(1.0-dSTART)) * (2.0/128.0*(1.0-dSTART))));
constexpr float  K_TSTEP = (float)((1.0 - dSTART) / (double)(NT - 1));
constexpr float  K_INVT  = (float)((double)(NT - 1) / (1.0 - dSTART));

__device__ __forceinline__ float silu_f(float x) {
    return x * __builtin_amdgcn_rcpf(1.0f + __expf(-x));
}

// ---------------- phase 1: LDS-multisplit coarse binning, 16 waves/block ----------------
// 196 blocks x 4096 edges: split into 256 bins in LDS, flush each bin's run with
// ONE global reservation -> contiguous full-line writes (mean 16 recs = 64 B).
// Also zeroes cnt[] (consumed by geo across a kernel boundary).
__global__ void __launch_bounds__(1024)
bin_kernel(const int* __restrict__ esrc, const int* __restrict__ edst,
           int* __restrict__ bincnt, unsigned* __restrict__ bins,
           int* __restrict__ cnt)
{
    __shared__ int      lcnt[NB];
    __shared__ unsigned lbuf[NB * LSTR];
    const int bid = blockIdx.x;
    const int tid = threadIdx.x;

    {   // zero cnt: 196*1024 = 200704 >= NND
        int i = bid * 1024 + tid;
        if (i < NND) cnt[i] = 0;
    }
    if (tid < NB) lcnt[tid] = 0;
    __syncthreads();

    const int e0 = bid * 4096;
    #pragma unroll
    for (int r = 0; r < 4; ++r) {
        int e = e0 + r * 1024 + tid;
        if (e < NED) {
            int dst = edst[e];
            int src = esrc[e];
            int b = dst / NPB;                       // const divide -> magic mul
            unsigned rec = ((unsigned)src << 8) | (unsigned)(dst - b * NPB);
            int p = atomicAdd(&lcnt[b], 1);
            if (p < LCAP) lbuf[b * LSTR + p] = rec;
            else {                                   // ~never: direct global append
                int gp = atomicAdd(&bincnt[b], 1);
                if (gp < BCAP) bins[b * BCAP + gp] = rec;
            }
        }
    }
    __syncthreads();
    // flush: thread tid (<256) owns bin tid; one reservation, contiguous run
    if (tid < NB) {
        int c = lcnt[tid]; c = c < LCAP ? c : LCAP;
        if (c > 0) {
            int base = atomicAdd(&bincnt[tid], c);
            for (int i = 0; i < c; ++i)
                if (base + i < BCAP) bins[tid * BCAP + base + i] = lbuf[tid * LSTR + i];
        }
    }
}

// ---------------- phase 2: per-bin geometry scatter || rad-table build ----------------
// Blocks [0,256): one block per coarse bin, 1024 threads (16 waves hide the
// random pos[src] latency). Fine-scatter window = 196 nodes x 1 KB -> XCD-L2
// local. Dead edges (d>=5) store (0,0,0,K_START) -> lerp lands exactly on
// table[0] == 0 == the reference's exact-zero message.
// Blocks [256,272): table MLP, 1 wave x 64 entries each (proven-fast spread);
// they also zero out[]. Table is consumed only by agg_head -> boundary-coherent.
__global__ void __launch_bounds__(1024)
geo_table(const float* __restrict__ pos,
          const int* __restrict__ bincnt, const unsigned* __restrict__ bins,
          int* __restrict__ cnt, float4* __restrict__ geo,
          const float* __restrict__ W1, const float* __restrict__ b1,
          const float* __restrict__ W2, const float* __restrict__ b2,
          const float* __restrict__ W3, float* __restrict__ table,
          float* __restrict__ out)
{
    __shared__ float hb[64][17];
    const int bid = blockIdx.x;
    const int tid = threadIdx.x;

    if (bid < GEO_BLOCKS) {
        int nb = bincnt[bid]; nb = nb < BCAP ? nb : BCAP;
        const int base_node = bid * NPB;
        for (int i = tid; i < nb; i += 1024) {
            unsigned rec = bins[bid * BCAP + i];
            int src = (int)(rec >> 8);
            int dst = base_node + (int)(rec & 255u);
            float vx = pos[3*src+0] - pos[3*dst+0];
            float vy = pos[3*src+1] - pos[3*dst+1];
            float vz = pos[3*src+2] - pos[3*dst+2];
            float d2 = vx*vx + vy*vy + vz*vz;
            float4 g;
            if (d2 < 25.0f) {
                float ddv = sqrtf(d2);
                float inv = 1.0f / fmaxf(ddv, 1e-12f);
                g = make_float4(vx*inv, vy*inv, vz*inv, __expf(-ddv));
            } else {
                g = make_float4(0.0f, 0.0f, 0.0f, K_START);
            }
            int p = atomicAdd(&cnt[dst], 1);
            if (p < CAP) geo[(size_t)dst * CAP + p] = g;
        }
        return;
    }

    // ---- table path: 1 wave per block ----
    if (tid >= 64) return;
    const int tb = bid - GEO_BLOCKS;                // 0..15
    #pragma unroll
    for (int k = 0; k < 2; ++k) out[tb * 128 + k * 64 + tid] = 0.0f;   // zero out[2048]

    const int ti = tb * 64 + tid;                   // 0..1023
    const int l  = tid;

    const float xe = K_START + K_TSTEP * (float)ti;
    const float dd = -logf(xe);
    const float cutv = (dd < 5.0f) ? (0.5f * (__cosf(dd * 0.6283185307179586f) + 1.0f)) : 0.0f;

    // layer 1: h1[j] = b1[j] + sum_k rbf[k] * W1[k][j]
    float h1[64];
    {
        const float4* bp = (const float4*)b1;
        #pragma unroll
        for (int j4 = 0; j4 < 16; ++j4) {
            float4 b = bp[j4];
            h1[4*j4+0] = b.x; h1[4*j4+1] = b.y; h1[4*j4+2] = b.z; h1[4*j4+3] = b.w;
        }
    }
    #pragma unroll 2
    for (int k = 0; k < 128; ++k) {
        float mean = K_START + K_STEP * (float)k;
        float t = xe - mean;
        float rk = cutv * __expf(-K_BETA * t * t);
        const float4* wr = (const float4*)(W1 + (k << 6));
        #pragma unroll
        for (int j4 = 0; j4 < 16; ++j4) {
            float4 wv = wr[j4];
            h1[4*j4+0] = fmaf(rk, wv.x, h1[4*j4+0]);
            h1[4*j4+1] = fmaf(rk, wv.y, h1[4*j4+1]);
            h1[4*j4+2] = fmaf(rk, wv.z, h1[4*j4+2]);
            h1[4*j4+3] = fmaf(rk, wv.w, h1[4*j4+3]);
        }
    }

    // layer 2 (chunked LDS for runtime-k activation reads)
    float h2[64];
    {
        const float4* bp = (const float4*)b2;
        #pragma unroll
        for (int j4 = 0; j4 < 16; ++j4) {
            float4 b = bp[j4];
            h2[4*j4+0] = b.x; h2[4*j4+1] = b.y; h2[4*j4+2] = b.z; h2[4*j4+3] = b.w;
        }
    }
    #pragma unroll
    for (int ch = 0; ch < 4; ++ch) {
        #pragma unroll
        for (int j = 0; j < 16; ++j) hb[l][j] = silu_f(h1[ch*16 + j]);
        for (int k = 0; k < 16; ++k) {
            float hk = hb[l][k];
            const float4* wr = (const float4*)(W2 + ((ch*16 + k) << 6));
            #pragma unroll
            for (int j4 = 0; j4 < 16; ++j4) {
                float4 wv = wr[j4];
                h2[4*j4+0] = fmaf(hk, wv.x, h2[4*j4+0]);
                h2[4*j4+1] = fmaf(hk, wv.y, h2[4*j4+1]);
                h2[4*j4+2] = fmaf(hk, wv.z, h2[4*j4+2]);
                h2[4*j4+3] = fmaf(hk, wv.w, h2[4*j4+3]);
            }
        }
    }

    // layer 3
    float rad[16];
    #pragma unroll
    for (int cc = 0; cc < 16; ++cc) rad[cc] = 0.0f;
    #pragma unroll
    for (int ch = 0; ch < 4; ++ch) {
        #pragma unroll
        for (int j = 0; j < 16; ++j) hb[l][j] = silu_f(h2[ch*16 + j]);
        for (int k = 0; k < 16; ++k) {
            float hk = hb[l][k];
            const float4* wr = (const float4*)(W3 + ((ch*16 + k) << 4));
            #pragma unroll
            for (int c4 = 0; c4 < 4; ++c4) {
                float4 wv = wr[c4];
                rad[4*c4+0] = fmaf(hk, wv.x, rad[4*c4+0]);
                rad[4*c4+1] = fmaf(hk, wv.y, rad[4*c4+1]);
                rad[4*c4+2] = fmaf(hk, wv.z, rad[4*c4+2]);
                rad[4*c4+3] = fmaf(hk, wv.w, rad[4*c4+3]);
            }
        }
    }

    float4* rp = (float4*)(table + (size_t)ti * 16);
    rp[0] = make_float4(rad[0],  rad[1],  rad[2],  rad[3]);
    rp[1] = make_float4(rad[4],  rad[5],  rad[6],  rad[7]);
    rp[2] = make_float4(rad[8],  rad[9],  rad[10], rad[11]);
    rp[3] = make_float4(rad[12], rad[13], rad[14], rad[15]);
}

// ---------------- phase 3: agg + head: shfl-free geo stream, zero barriers ----------------
// 8 nodes/wave (8-lane groups, 2 channels/lane); group streams its node's geo
// bucket as broadcast float4 loads (no random reads, no shfl). Table is 64 KB
// -> L1/L2-hot lerp. All LDS same-wave -> no barriers. 128 thr, 9.2 KB LDS.
__global__ void __launch_bounds__(128)
agg_head(const int* __restrict__ cnt, const float4* __restrict__ geo,
         const float* __restrict__ table,
         const float* __restrict__ atom_table, const int* __restrict__ node_atom,
         const int* __restrict__ batch,
         const float* __restrict__ Wh1, const float* __restrict__ bh1,
         const float* __restrict__ Wh2, const float* __restrict__ bh2,
         float* __restrict__ out, float isd, float isn)
{
    __shared__ float nf_s[2][8][144];
    const int tid  = threadIdx.x;
    const int lane = tid & 63;
    const int wv   = tid >> 6;
    const int g    = lane >> 3;          // node slot within wave
    const int c    = lane & 7;           // channels c and c+8
    const int n    = blockIdx.x * 16 + wv * 8 + g;   // 3125 blocks * 16 = 50000 exact

    float acc0[9], acc1[9];
    #pragma unroll
    for (int s = 0; s < 9; ++s) { acc0[s] = 0.0f; acc1[s] = 0.0f; }

    int deg = cnt[n]; deg = deg < CAP ? deg : CAP;
    const float4* myg = geo + (size_t)n * CAP;

    for (int p = 0; p < deg; ++p) {
        float4 gv = myg[p];              // broadcast within 8-lane group
        float ux = gv.x, uy = gv.y, uz = gv.z, xe = gv.w;

        float t = (xe - K_START) * K_INVT;
        int i0 = (int)t;
        i0 = i0 < 0 ? 0 : (i0 > NT-2 ? NT-2 : i0);
        float fr = t - (float)i0;
        const float* tb = table + (size_t)i0 * 16 + c;
        float r0a = tb[0], r1a = tb[16];
        float r0b = tb[8], r1b = tb[24];
        float ra = fmaf(fr, r1a - r0a, r0a);   // channel c
        float rb = fmaf(fr, r1b - r0b, r0b);   // channel c+8

        float sh1 = 1.7320508075688772f * ux;
        float sh2 = 1.7320508075688772f * uy;
        float sh3 = 1.7320508075688772f * uz;
        float sh4 = 3.872983346207417f * ux * uz;
        float sh5 = 3.872983346207417f * ux * uy;
        float sh6 = 2.23606797749979f * (uy*uy - 0.5f*(ux*ux + uz*uz));
        float sh7 = 3.872983346207417f * uy * uz;
        float sh8 = 1.9364916731037085f * (uz*uz - ux*ux);

        acc0[0] += ra;                    acc1[0] += rb;
        acc0[1] = fmaf(ra, sh1, acc0[1]); acc1[1] = fmaf(rb, sh1, acc1[1]);
        acc0[2] = fmaf(ra, sh2, acc0[2]); acc1[2] = fmaf(rb, sh2, acc1[2]);
        acc0[3] = fmaf(ra, sh3, acc0[3]); acc1[3] = fmaf(rb, sh3, acc1[3]);
        acc0[4] = fmaf(ra, sh4, acc0[4]); acc1[4] = fmaf(rb, sh4, acc1[4]);
        acc0[5] = fmaf(ra, sh5, acc0[5]); acc1[5] = fmaf(rb, sh5, acc1[5]);
        acc0[6] = fmaf(ra, sh6, acc0[6]); acc1[6] = fmaf(rb, sh6, acc1[6]);
        acc0[7] = fmaf(ra, sh7, acc0[7]); acc1[7] = fmaf(rb, sh7, acc1[7]);
        acc0[8] = fmaf(ra, sh8, acc0[8]); acc1[8] = fmaf(rb, sh8, acc1[8]);
    }

    // nf = atom_table[atom] + deg_embed * isd -> this wave's LDS slab
    {
        int a = node_atom[n];
        const float* at = atom_table + (size_t)a * 144;
        #pragma unroll
        for (int s = 0; s < 9; ++s) {
            nf_s[wv][g][c*9 + s]     = fmaf(acc0[s], isd, at[c*9 + s]);
            nf_s[wv][g][(c+8)*9 + s] = fmaf(acc1[s], isd, at[(c+8)*9 + s]);
        }
    }
    // same-wave LDS write->read: hardware-ordered, no barrier

    // head: hn = silu(nf @ Wh1 + bh1); energy = hn @ Wh2 + bh2
    float A0[8], A1[8], A2[8];
    {
        float bb0 = bh1[lane], bb1 = bh1[lane + 64];
        float bb2 = (lane < 16) ? bh1[lane + 128] : 0.0f;
        #pragma unroll
        for (int q = 0; q < 8; ++q) { A0[q] = bb0; A1[q] = bb1; A2[q] = bb2; }
    }

    for (int k4 = 0; k4 < 36; ++k4) {
        float4 nq[8];
        #pragma unroll
        for (int q = 0; q < 8; ++q)
            nq[q] = *(const float4*)&nf_s[wv][q][k4*4];      // LDS broadcast
        const float* wrow = Wh1 + (size_t)(k4*4) * 144;      // L2-hot global
#define HSTEP(COMP, OFF) { \
        float w0 = wrow[(OFF)*144 + lane]; \
        float w1 = wrow[(OFF)*144 + lane + 64]; \
        float w2 = (lane < 16) ? wrow[(OFF)*144 + lane + 128] : 0.0f; \
        _Pragma("unroll") \
        for (int q = 0; q < 8; ++q) { \
            float nk = nq[q].COMP; \
            A0[q] = fmaf(nk, w0, A0[q]); \
            A1[q] = fmaf(nk, w1, A1[q]); \
            A2[q] = fmaf(nk, w2, A2[q]); } }
        HSTEP(x, 0) HSTEP(y, 1) HSTEP(z, 2) HSTEP(w, 3)
#undef HSTEP
    }

    float wl0 = Wh2[lane], wl1 = Wh2[lane + 64];
    float wl2 = (lane < 16) ? Wh2[lane + 128] : 0.0f;
    float bv  = bh2[0];
    #pragma unroll
    for (int q = 0; q < 8; ++q) {
        float en = silu_f(A0[q]) * wl0 + silu_f(A1[q]) * wl1;
        if (lane < 16) en = fmaf(silu_f(A2[q]), wl2, en);
        en += __shfl_down(en, 32);
        en += __shfl_down(en, 16);
        en += __shfl_down(en, 8);
        en += __shfl_down(en, 4);
        en += __shfl_down(en, 2);
        en += __shfl_down(en, 1);
        if (lane == 0) {
            int nq_ = blockIdx.x * 16 + wv * 8 + q;
            unsafeAtomicAdd(out + batch[nq_], (en + bv) * isn);
        }
    }
}

extern "C" void kernel_launch(void* const* d_in, const int* in_sizes, int n_in,
                              void* d_out, int out_size, void* d_ws, size_t ws_size,
                              hipStream_t stream) {
    const float* pos        = (const float*)d_in[0];
    const float* atom_table = (const float*)d_in[1];
    const float* W1         = (const float*)d_in[2];
    const float* b1         = (const float*)d_in[3];
    const float* W2         = (const float*)d_in[4];
    const float* b2         = (const float*)d_in[5];
    const float* W3         = (const float*)d_in[6];
    const float* Wh1        = (const float*)d_in[7];
    const float* bh1        = (const float*)d_in[8];
    const float* Wh2        = (const float*)d_in[9];
    const float* bh2        = (const float*)d_in[10];
    const int*   node_atom  = (const int*)d_in[11];
    const int*   edge_src   = (const int*)d_in[12];
    const int*   edge_dst   = (const int*)d_in[13];
    const int*   batch      = (const int*)d_in[14];

    float* out = (float*)d_out;

    // workspace layout (16B-aligned where needed)
    char*     wsb    = (char*)d_ws;
    int*      cnt    = (int*)(wsb);                  // [NND]        200000 B
    int*      bincnt = (int*)(wsb + 200000);         // [NB]         1024 B
    float*    table  = (float*)(wsb + 201728);       // [NT][16]     65536 B (16B-al)
    unsigned* bins   = (unsigned*)(wsb + 267264);    // [NB][BCAP]   3.93 MB
    float4*   geo    = (float4*)(wsb + 4199424);     // [NND][CAP]   51.2 MB (16B-al)

    hipMemsetAsync(bincnt, 0, NB * 4, stream);

    bin_kernel<<<BIN_BLOCKS, 1024, 0, stream>>>(edge_src, edge_dst, bincnt, bins, cnt);

    geo_table<<<GEO_BLOCKS + TBL_BLOCKS, 1024, 0, stream>>>(
        pos, bincnt, bins, cnt, geo, W1, b1, W2, b2, W3, table, out);

    float isd = 1.0f / sqrtf(15.57930850982666f);
    float isn = 1.0f / sqrtf(18.03065905448718f);
    agg_head<<<NND / 16, 128, 0, stream>>>(
        cnt, geo, table, atom_table, node_atom, batch,
        Wh1, bh1, Wh2, bh2, out, isd, isn);
}